// Round 1
// baseline (537.660 us; speedup 1.0000x reference)
//
#include <hip/hip_runtime.h>

typedef unsigned short u16;
typedef __bf16 bf16x8 __attribute__((ext_vector_type(8)));
typedef float f32x4 __attribute__((ext_vector_type(4)));
typedef u16 u16x8 __attribute__((ext_vector_type(8)));
typedef u16 u16x4 __attribute__((ext_vector_type(4)));

__device__ __forceinline__ u16 f2bf(float f) {
    union { float f; unsigned u; } v; v.f = f;
    unsigned r = v.u + 0x7FFFu + ((v.u >> 16) & 1u);
    return (u16)(r >> 16);
}

#define AS1 __attribute__((address_space(1)))
#define AS3 __attribute__((address_space(3)))
__device__ __forceinline__ void gload_lds16(const void* g, void* l) {
    __builtin_amdgcn_global_load_lds((const AS1 void*)(g), (AS3 void*)(l), 16, 0, 0);
}

// ---------------- prep: roll(-6,-6) + window partition + cast to bf16 ----------------
// xw[(b*4 + wh*2+ww)*144 + r*12+cc][c] = x[b][(wh*12+r+6)%24][(ww*12+cc+6)%24][c]
__global__ __launch_bounds__(256) void prep_x_kernel(const float* __restrict__ x, u16* __restrict__ xw) {
    unsigned i = ((unsigned)blockIdx.x * 256u + threadIdx.x) * 4u;  // element index, total 36864*768
    int R = (int)(i / 768u); int c = (int)(i % 768u);
    int w = R / 144, nn = R - w * 144;
    int b = w >> 2, wi = w & 3;
    int r = nn / 12, cc = nn - r * 12;
    int sh = (wi >> 1) * 12 + r + 6; if (sh >= 24) sh -= 24;
    int sw = (wi & 1) * 12 + cc + 6; if (sw >= 24) sw -= 24;
    const float* src = x + (((size_t)b * 24 + sh) * 24 + sw) * 768 + c;
    f32x4 v = *(const f32x4*)src;
    u16x4 o; o[0] = f2bf(v[0]); o[1] = f2bf(v[1]); o[2] = f2bf(v[2]); o[3] = f2bf(v[3]);
    *(u16x4*)(xw + i) = o;
}

// ---------------- weight transpose + cast: w[K][N] -> wt[N][K] bf16 ----------------
__global__ __launch_bounds__(256) void transpose_cast_kernel(const float* __restrict__ w, u16* __restrict__ wt,
                                                             int K, int N) {
    __shared__ float tile[32][33];
    int tx = threadIdx.x & 31, ty = threadIdx.x >> 5;  // ty 0..7
    int nb = blockIdx.x * 32, kb = blockIdx.y * 32;
#pragma unroll
    for (int rr = 0; rr < 32; rr += 8) tile[rr + ty][tx] = w[(size_t)(kb + rr + ty) * N + nb + tx];
    __syncthreads();
#pragma unroll
    for (int rr = 0; rr < 32; rr += 8) wt[(size_t)(nb + rr + ty) * K + kb + tx] = f2bf(tile[tx][rr + ty]);
}

// ---------------- bias_mat[h][n][m] = rpb_table[rel_index[n*144+m]][h] ----------------
__global__ __launch_bounds__(256) void make_bias_kernel(const float* __restrict__ tab, const int* __restrict__ rel,
                                                        float* __restrict__ bm) {
    int i = blockIdx.x * 256 + threadIdx.x;  // grid exactly 24*20736
    int h = i / 20736, nm = i - h * 20736;
    bm[i] = tab[rel[nm] * 24 + h];
}

// ---------------- 128x128 BK=32 bf16 MFMA GEMM (m97 structure), Bt layout ----------------
// EPI 0: out -> Q(scaled)/K as [win][head][144][32], V transposed [win][head][32][144]
// EPI 1: out -> fp32 of[R*N + Cg] (+bias)
template <int EPI>
__global__ __launch_bounds__(256) void gemm128_kernel(const u16* __restrict__ A, const u16* __restrict__ Bt,
                                                      const float* __restrict__ bias,
                                                      u16* __restrict__ o0, u16* __restrict__ o1, u16* __restrict__ o2,
                                                      float* __restrict__ of, int N, int K, float qscale) {
    __shared__ __align__(16) u16 As[128 * 32];
    __shared__ __align__(16) u16 Bs[128 * 32];
    const int t = threadIdx.x, lane = t & 63, wave = t >> 6;
    const int bm = blockIdx.y << 7, bn = blockIdx.x << 7;
    const int wr = wave >> 1, wc = wave & 1;
    const int l15 = lane & 15, lg = lane >> 4;
    f32x4 acc[4][4] = {};
    const int ar = t >> 2, acx = (t & 3) << 3;
    const u16* ga = A + (size_t)(bm + ar) * K + acx;
    const u16* gb = Bt + (size_t)(bn + ar) * K + acx;
    const size_t rowoff = (size_t)64 * K;
    for (int kk = 0; kk < K; kk += 32) {
        gload_lds16(ga + kk, As + wave * 512);
        gload_lds16(ga + kk + rowoff, As + 2048 + wave * 512);
        gload_lds16(gb + kk, Bs + wave * 512);
        gload_lds16(gb + kk + rowoff, Bs + 2048 + wave * 512);
        __syncthreads();
        bf16x8 af[4], bfv[4];
#pragma unroll
        for (int m = 0; m < 4; m++) af[m] = *(const bf16x8*)(As + (wr * 64 + m * 16 + l15) * 32 + lg * 8);
#pragma unroll
        for (int n = 0; n < 4; n++) bfv[n] = *(const bf16x8*)(Bs + (wc * 64 + n * 16 + l15) * 32 + lg * 8);
#pragma unroll
        for (int m = 0; m < 4; m++)
#pragma unroll
            for (int n = 0; n < 4; n++)
                acc[m][n] = __builtin_amdgcn_mfma_f32_16x16x32_bf16(af[m], bfv[n], acc[m][n], 0, 0, 0);
        __syncthreads();
    }
#pragma unroll
    for (int m = 0; m < 4; m++) {
        int Rbase = bm + wr * 64 + m * 16 + lg * 4;
#pragma unroll
        for (int n = 0; n < 4; n++) {
            int Cg = bn + wc * 64 + n * 16 + l15;
            float bv = bias[Cg];
            if (EPI == 0) {
                int s = Cg / 768; int rem = Cg - s * 768; int h = rem >> 5; int dd = rem & 31;
#pragma unroll
                for (int rg = 0; rg < 4; rg++) {
                    int R = Rbase + rg;
                    int w = R / 144; int nn = R - w * 144;
                    float v = acc[m][n][rg] + bv;
                    if (s == 0)      o0[((size_t)(w * 24 + h) * 144 + nn) * 32 + dd] = f2bf(v * qscale);
                    else if (s == 1) o1[((size_t)(w * 24 + h) * 144 + nn) * 32 + dd] = f2bf(v);
                    else             o2[((size_t)(w * 24 + h) * 32 + dd) * 144 + nn] = f2bf(v);
                }
            } else {
#pragma unroll
                for (int rg = 0; rg < 4; rg++) {
                    int R = Rbase + rg;
                    of[(size_t)R * N + Cg] = acc[m][n][rg] + bv;
                }
            }
        }
    }
}

// ---------------- fused window attention: 1 block per (window, head), 9 waves ----------------
__global__ __launch_bounds__(576) void attn_kernel(const u16* __restrict__ Qg, const u16* __restrict__ Kg,
                                                   const u16* __restrict__ Vg, const float* __restrict__ bias_mat,
                                                   u16* __restrict__ Ob) {
    __shared__ __align__(16) u16 Qs[144 * 40];
    __shared__ __align__(16) u16 Ks[144 * 40];
    __shared__ __align__(16) u16 Vs[32 * 160];    // swizzled rows (byte ^ ((row&7)<<4))
    __shared__ __align__(16) u16 Ps[144 * 160];   // swizzled rows
    const int bx = blockIdx.x;
    const int w = bx / 24, h = bx - w * 24;
    const int wi = w & 3, wh = wi >> 1, ww = wi & 1;
    const int t = threadIdx.x, lane = t & 63, wv = t >> 6;
    const int l15 = lane & 15, lg = lane >> 4;
    const size_t base = (size_t)bx * 4608;  // 144*32
    {
        int nn = t >> 2, dd = (t & 3) << 3;
        *(u16x8*)(Qs + nn * 40 + dd) = *(const u16x8*)(Qg + base + nn * 32 + dd);
        *(u16x8*)(Ks + nn * 40 + dd) = *(const u16x8*)(Kg + base + nn * 32 + dd);
        int rv = t / 18, cv = (t - rv * 18) * 8;
        int ba = (rv * 320 + cv * 2) ^ ((rv & 7) << 4);
        *(u16x8*)((char*)Vs + ba) = *(const u16x8*)(Vg + base + rv * 144 + cv);
    }
    u16x8 zz = (u16x8)0;
    if (t < 64)  { int rv = t >> 1, cv = 144 + (t & 1) * 8; int ba = (rv * 320 + cv * 2) ^ ((rv & 7) << 4); *(u16x8*)((char*)Vs + ba) = zz; }
    if (t < 288) { int rv = t >> 1, cv = 144 + (t & 1) * 8; int ba = (rv * 320 + cv * 2) ^ ((rv & 7) << 4); *(u16x8*)((char*)Ps + ba) = zz; }
    __syncthreads();

    // QK^T: wave wv owns S rows [16wv, 16wv+16)
    f32x4 S[9];
    {
        bf16x8 aq = *(const bf16x8*)(Qs + (wv * 16 + l15) * 40 + lg * 8);
        f32x4 z4 = (f32x4)0.0f;
#pragma unroll
        for (int j = 0; j < 9; j++) {
            bf16x8 bk = *(const bf16x8*)(Ks + (j * 16 + l15) * 40 + lg * 8);
            S[j] = __builtin_amdgcn_mfma_f32_16x16x32_bf16(aq, bk, z4, 0, 0, 0);
        }
    }
    // region ids for the shift mask (analytic)
    int regm[9];
#pragma unroll
    for (int j = 0; j < 9; j++) {
        int m = j * 16 + l15; int r = m / 12, c = m - r * 12;
        int rid = wh ? (r < 6 ? 1 : 2) : 0;
        int cid = ww ? (c < 6 ? 1 : 2) : 0;
        regm[j] = rid * 3 + cid;
    }
    const float* bh = bias_mat + h * 20736;
#pragma unroll
    for (int rg = 0; rg < 4; rg++) {
        int n = wv * 16 + lg * 4 + rg;
        int r = n / 12, c = n - r * 12;
        int rid = wh ? (r < 6 ? 1 : 2) : 0;
        int cid = ww ? (c < 6 ? 1 : 2) : 0;
        int regn = rid * 3 + cid;
        const float* bhn = bh + n * 144;
        float mx = -1e30f;
#pragma unroll
        for (int j = 0; j < 9; j++) {
            float v = S[j][rg] + bhn[j * 16 + l15];
            if (regn != regm[j]) v -= 100.0f;
            S[j][rg] = v;
            mx = fmaxf(mx, v);
        }
#pragma unroll
        for (int d = 1; d < 16; d <<= 1) mx = fmaxf(mx, __shfl_xor(mx, d));
        float sum = 0.0f;
#pragma unroll
        for (int j = 0; j < 9; j++) { float e = __expf(S[j][rg] - mx); S[j][rg] = e; sum += e; }
#pragma unroll
        for (int d = 1; d < 16; d <<= 1) sum += __shfl_xor(sum, d);
        float inv = 1.0f / sum;
#pragma unroll
        for (int j = 0; j < 9; j++) {
            int ba = (n * 320 + (j * 16 + l15) * 2) ^ ((n & 7) << 4);
            *(u16*)((char*)Ps + ba) = f2bf(S[j][rg] * inv);
        }
    }
    __syncthreads();
    // PV: O[n][d] = sum_k P[n][k] V[k][d], K padded 144->160 with zeros
    f32x4 o0 = (f32x4)0.0f, o1 = (f32x4)0.0f;
#pragma unroll
    for (int ks = 0; ks < 5; ks++) {
        int k2 = (ks * 32 + lg * 8) * 2;
        int ra = wv * 16 + l15;
        bf16x8 ap = *(const bf16x8*)((char*)Ps + ((ra * 320 + k2) ^ ((ra & 7) << 4)));
        int rv0 = l15, rv1 = 16 + l15;
        bf16x8 b0 = *(const bf16x8*)((char*)Vs + ((rv0 * 320 + k2) ^ ((rv0 & 7) << 4)));
        bf16x8 b1 = *(const bf16x8*)((char*)Vs + ((rv1 * 320 + k2) ^ ((rv1 & 7) << 4)));
        o0 = __builtin_amdgcn_mfma_f32_16x16x32_bf16(ap, b0, o0, 0, 0, 0);
        o1 = __builtin_amdgcn_mfma_f32_16x16x32_bf16(ap, b1, o1, 0, 0, 0);
    }
    size_t ob = (size_t)w * 110592 + (size_t)h * 32;  // [B*nW][144][768]
#pragma unroll
    for (int rg = 0; rg < 4; rg++) {
        int n = wv * 16 + lg * 4 + rg;
        Ob[ob + (size_t)n * 768 + l15]      = f2bf(o0[rg]);
        Ob[ob + (size_t)n * 768 + 16 + l15] = f2bf(o1[rg]);
    }
}

// ---------------- L2 norm + window-merge + reverse shift ----------------
__global__ __launch_bounds__(256) void norm_kernel(const float* __restrict__ raw, float* __restrict__ out) {
    int R = blockIdx.x * 4 + (threadIdx.x >> 6);
    int lane = threadIdx.x & 63;
    const float* src = raw + (size_t)R * 768;
    f32x4 v0 = *(const f32x4*)(src + lane * 4);
    f32x4 v1 = *(const f32x4*)(src + lane * 4 + 256);
    f32x4 v2 = *(const f32x4*)(src + lane * 4 + 512);
    float ss = v0[0]*v0[0] + v0[1]*v0[1] + v0[2]*v0[2] + v0[3]*v0[3]
             + v1[0]*v1[0] + v1[1]*v1[1] + v1[2]*v1[2] + v1[3]*v1[3]
             + v2[0]*v2[0] + v2[1]*v2[1] + v2[2]*v2[2] + v2[3]*v2[3];
#pragma unroll
    for (int d = 1; d < 64; d <<= 1) ss += __shfl_xor(ss, d);
    float inv = 1.0f / sqrtf(ss + 1e-6f);
    int w = R / 144, nn = R - w * 144;
    int b = w >> 2, wi = w & 3;
    int r = nn / 12, cc = nn - r * 12;
    int oh = (wi >> 1) * 12 + r + 6; if (oh >= 24) oh -= 24;
    int ow = (wi & 1) * 12 + cc + 6; if (ow >= 24) ow -= 24;
    float* dst = out + (((size_t)b * 24 + oh) * 24 + ow) * 768;
    v0 *= inv; v1 *= inv; v2 *= inv;
    *(f32x4*)(dst + lane * 4) = v0;
    *(f32x4*)(dst + lane * 4 + 256) = v1;
    *(f32x4*)(dst + lane * 4 + 512) = v2;
}

extern "C" void kernel_launch(void* const* d_in, const int* in_sizes, int n_in,
                              void* d_out, int out_size, void* d_ws, size_t ws_size,
                              hipStream_t stream) {
    const float* x      = (const float*)d_in[0];
    const float* qkv_w  = (const float*)d_in[1];
    const float* qkv_b  = (const float*)d_in[2];
    const float* proj_w = (const float*)d_in[3];
    const float* proj_b = (const float*)d_in[4];
    const float* rpb    = (const float*)d_in[5];
    const int*   rel    = (const int*)d_in[6];

    char* ws = (char*)d_ws;
    const size_t SZ = 56623104;  // 36864*768*2 bytes
    u16*   xw   = (u16*)(ws);
    u16*   Qb   = (u16*)(ws + SZ);
    u16*   Kb   = (u16*)(ws + 2 * SZ);
    u16*   Vt   = (u16*)(ws + 3 * SZ);
    u16*   Ob   = (u16*)(ws + 4 * SZ);
    u16*   qwt  = (u16*)(ws + 5 * SZ);                       // 3,538,944 B
    u16*   pwt  = (u16*)(ws + 5 * SZ + 3538944);             // 1,179,648 B
    float* bm   = (float*)(ws + 5 * SZ + 3538944 + 1179648); // 1,990,656 B
    float* raw  = (float*)(ws);  // aliases xw+Qb (dead by the time GEMM2 runs)

    prep_x_kernel<<<27648, 256, 0, stream>>>(x, xw);
    transpose_cast_kernel<<<dim3(72, 24), 256, 0, stream>>>(qkv_w, qwt, 768, 2304);
    transpose_cast_kernel<<<dim3(24, 24), 256, 0, stream>>>(proj_w, pwt, 768, 768);
    make_bias_kernel<<<1944, 256, 0, stream>>>(rpb, rel, bm);

    gemm128_kernel<0><<<dim3(18, 288), 256, 0, stream>>>(xw, qwt, qkv_b, Qb, Kb, Vt, nullptr,
                                                         2304, 768, 0.17677669529663687f);
    attn_kernel<<<6144, 576, 0, stream>>>(Qb, Kb, Vt, bm, Ob);
    gemm128_kernel<1><<<dim3(6, 288), 256, 0, stream>>>(Ob, pwt, proj_b, nullptr, nullptr, nullptr,
                                                        raw, 768, 768, 1.0f);
    norm_kernel<<<9216, 256, 0, stream>>>(raw, (float*)d_out);
}

// Round 2
// 517.245 us; speedup vs baseline: 1.0395x; 1.0395x over previous
//
#include <hip/hip_runtime.h>

typedef unsigned short u16;
typedef __bf16 bf16x8 __attribute__((ext_vector_type(8)));
typedef float f32x4 __attribute__((ext_vector_type(4)));
typedef u16 u16x8 __attribute__((ext_vector_type(8)));
typedef u16 u16x4 __attribute__((ext_vector_type(4)));

__device__ __forceinline__ u16 f2bf(float f) {
    union { float f; unsigned u; } v; v.f = f;
    unsigned r = v.u + 0x7FFFu + ((v.u >> 16) & 1u);
    return (u16)(r >> 16);
}

#define AS1 __attribute__((address_space(1)))
#define AS3 __attribute__((address_space(3)))
__device__ __forceinline__ void gload_lds16(const void* g, void* l) {
    __builtin_amdgcn_global_load_lds((const AS1 void*)(g), (AS3 void*)(l), 16, 0, 0);
}

// ---------------- prep: roll(-6,-6) + window partition + cast to bf16 ----------------
__global__ __launch_bounds__(256) void prep_x_kernel(const float* __restrict__ x, u16* __restrict__ xw) {
    unsigned i = ((unsigned)blockIdx.x * 256u + threadIdx.x) * 4u;
    int R = (int)(i / 768u); int c = (int)(i % 768u);
    int w = R / 144, nn = R - w * 144;
    int b = w >> 2, wi = w & 3;
    int r = nn / 12, cc = nn - r * 12;
    int sh = (wi >> 1) * 12 + r + 6; if (sh >= 24) sh -= 24;
    int sw = (wi & 1) * 12 + cc + 6; if (sw >= 24) sw -= 24;
    const float* src = x + (((size_t)b * 24 + sh) * 24 + sw) * 768 + c;
    f32x4 v = *(const f32x4*)src;
    u16x4 o; o[0] = f2bf(v[0]); o[1] = f2bf(v[1]); o[2] = f2bf(v[2]); o[3] = f2bf(v[3]);
    *(u16x4*)(xw + i) = o;
}

// ---------------- weight transpose + cast: w[K][N] -> wt[N][K] bf16 ----------------
__global__ __launch_bounds__(256) void transpose_cast_kernel(const float* __restrict__ w, u16* __restrict__ wt,
                                                             int K, int N) {
    __shared__ float tile[32][33];
    int tx = threadIdx.x & 31, ty = threadIdx.x >> 5;
    int nb = blockIdx.x * 32, kb = blockIdx.y * 32;
#pragma unroll
    for (int rr = 0; rr < 32; rr += 8) tile[rr + ty][tx] = w[(size_t)(kb + rr + ty) * N + nb + tx];
    __syncthreads();
#pragma unroll
    for (int rr = 0; rr < 32; rr += 8) wt[(size_t)(nb + rr + ty) * K + kb + tx] = f2bf(tile[tx][rr + ty]);
}

// ---------------- bias_mat[h][n][m] = rpb_table[rel_index[n*144+m]][h] ----------------
__global__ __launch_bounds__(256) void make_bias_kernel(const float* __restrict__ tab, const int* __restrict__ rel,
                                                        float* __restrict__ bm) {
    int i = blockIdx.x * 256 + threadIdx.x;
    int h = i / 20736, nm = i - h * 20736;
    bm[i] = tab[rel[nm] * 24 + h];
}

// ---------------- 256x256 BK=64 8-phase bf16 MFMA GEMM (T2+T3+T4+T5), Bt layout ----------------
// LDS: 2 buffers x 64KB; buffer b: A region [256r x 128B] at b*65536, B region at +32768.
// st_16x32 swizzle: region byte x stored at x ^ (((x>>9)&1)<<5)  (bit9 == (row>>2)&1).
#define FENCE asm volatile("" ::: "memory")
#define BARRIER __builtin_amdgcn_s_barrier()

#define STAGE_HALF(g, rowbase, region, buf, T, h)                                              \
    { _Pragma("unroll") for (int j = 0; j < 2; j++) {                                          \
        int Lb = (h) * 16384 + (j * 8 + wv) * 1024;                                            \
        int L = Lb + lane * 16;                                                                \
        int Ls = L ^ (((lane >> 5) & 1) << 5);                                                 \
        const u16* src = (g) + (size_t)((rowbase) + (Ls >> 7)) * Kdim + (T) * 64 + ((Ls & 127) >> 1); \
        gload_lds16(src, (char*)lds + (buf) * 65536 + (region) + Lb);                          \
    } }

#define READ_A(buf, mh)                                                                        \
    { _Pragma("unroll") for (int mf = 0; mf < 4; mf++) {                                       \
        _Pragma("unroll") for (int kk = 0; kk < 2; kk++) {                                     \
            int row = wr * 128 + (mh) * 64 + mf * 16 + l15;                                    \
            int cb = kk * 64 + lg * 16;                                                        \
            aR[mf][kk] = *(const bf16x8*)((const char*)lds + (buf) * 65536 + row * 128 + (cb ^ (((row >> 2) & 1) << 5))); \
    } } }

#define READ_B(buf, nh)                                                                        \
    { _Pragma("unroll") for (int nf = 0; nf < 2; nf++) {                                       \
        _Pragma("unroll") for (int kk = 0; kk < 2; kk++) {                                     \
            int row = wc * 64 + (nh) * 32 + nf * 16 + l15;                                     \
            int cb = kk * 64 + lg * 16;                                                        \
            bR[nh][nf][kk] = *(const bf16x8*)((const char*)lds + (buf) * 65536 + 32768 + row * 128 + (cb ^ (((row >> 2) & 1) << 5))); \
    } } }

#define MFMA_QUAD(mh, nh)                                                                      \
    { __builtin_amdgcn_s_setprio(1);                                                           \
      _Pragma("unroll") for (int mf = 0; mf < 4; mf++) {                                       \
        _Pragma("unroll") for (int nf = 0; nf < 2; nf++) {                                     \
            _Pragma("unroll") for (int kk = 0; kk < 2; kk++) {                                 \
                acc[(mh) * 4 + mf][(nh) * 2 + nf] = __builtin_amdgcn_mfma_f32_16x16x32_bf16(   \
                    aR[mf][kk], bR[nh][nf][kk], acc[(mh) * 4 + mf][(nh) * 2 + nf], 0, 0, 0);   \
      } } }                                                                                    \
      __builtin_amdgcn_s_setprio(0); }

template <int EPI>
__global__ __launch_bounds__(512, 2) void gemm256_kernel(const u16* __restrict__ A, const u16* __restrict__ Bt,
                                                         const float* __restrict__ bias,
                                                         u16* __restrict__ o0, u16* __restrict__ o1, u16* __restrict__ o2,
                                                         float* __restrict__ of, int Ndim, int Kdim, int nxb, float qscale) {
    __shared__ __align__(16) u16 lds[65536];  // 128 KiB
    const int t = threadIdx.x, lane = t & 63, wv = t >> 6;
    const int wr = wv >> 2, wc = wv & 3;          // 2 x 4 wave grid
    const int l15 = lane & 15, lg = lane >> 4;
    int nwg = gridDim.x, orig = blockIdx.x;       // bijective XCD swizzle
    int q = nwg >> 3, r = nwg & 7, xcd = orig & 7, loc = orig >> 3;
    int wg = (xcd < r ? xcd * (q + 1) : r * (q + 1) + (xcd - r) * q) + loc;
    int by = wg / nxb, bx = wg - by * nxb;
    const int bm = by << 8, bn = bx << 8;

    f32x4 acc[8][4] = {};
    bf16x8 aR[4][2];      // current A quadrant [mf][kk]
    bf16x8 bR[2][2][2];   // B [nh][nf][kk], both halves live

    const int NT = Kdim >> 6;      // 12
    const int NITER = NT >> 1;     // 6

    // prologue: T0 (all 4 halves) + T1 B0,A0
    STAGE_HALF(A, bm, 0, 0, 0, 0);
    STAGE_HALF(A, bm, 0, 0, 0, 1);
    STAGE_HALF(Bt, bn, 32768, 0, 0, 0);
    STAGE_HALF(Bt, bn, 32768, 0, 0, 1);
    STAGE_HALF(Bt, bn, 32768, 1, 1, 0);
    STAGE_HALF(A, bm, 0, 1, 1, 0);
    asm volatile("s_waitcnt vmcnt(4)" ::: "memory");
    FENCE; BARRIER;

    for (int i = 0; i < NITER; i++) {
        const int u = 2 * i + 1, t2 = 2 * i + 2, t3 = 2 * i + 3;
        const bool last = (i == NITER - 1);
        // ---- tile 2i from buf0 ----
        // p1
        READ_A(0, 0); READ_B(0, 0);
        STAGE_HALF(Bt, bn, 32768, 1, u, 1);
        FENCE; BARRIER;
        MFMA_QUAD(0, 0);
        FENCE; BARRIER;
        // p2
        READ_B(0, 1);
        STAGE_HALF(A, bm, 0, 1, u, 1);
        FENCE; BARRIER;
        MFMA_QUAD(0, 1);
        FENCE; BARRIER;
        // p3
        READ_A(0, 1);
        if (t2 < NT) STAGE_HALF(Bt, bn, 32768, 0, t2, 0);
        FENCE; BARRIER;
        MFMA_QUAD(1, 0);
        FENCE; BARRIER;
        // p4
        if (t2 < NT) STAGE_HALF(A, bm, 0, 0, t2, 0);
        FENCE; BARRIER;
        MFMA_QUAD(1, 1);
        if (last) { asm volatile("s_waitcnt vmcnt(0)" ::: "memory"); }
        else      { asm volatile("s_waitcnt vmcnt(4)" ::: "memory"); }
        FENCE; BARRIER;
        // ---- tile 2i+1 from buf1 ----
        // p5
        READ_A(1, 0); READ_B(1, 0);
        if (t2 < NT) STAGE_HALF(Bt, bn, 32768, 0, t2, 1);
        FENCE; BARRIER;
        MFMA_QUAD(0, 0);
        FENCE; BARRIER;
        // p6
        READ_B(1, 1);
        if (t2 < NT) STAGE_HALF(A, bm, 0, 0, t2, 1);
        FENCE; BARRIER;
        MFMA_QUAD(0, 1);
        FENCE; BARRIER;
        // p7
        READ_A(1, 1);
        if (t3 < NT) STAGE_HALF(Bt, bn, 32768, 1, t3, 0);
        FENCE; BARRIER;
        MFMA_QUAD(1, 0);
        FENCE; BARRIER;
        // p8
        if (t3 < NT) STAGE_HALF(A, bm, 0, 1, t3, 0);
        FENCE; BARRIER;
        MFMA_QUAD(1, 1);
        asm volatile("s_waitcnt vmcnt(4)" ::: "memory");
        FENCE; BARRIER;
    }

    // epilogue
#pragma unroll
    for (int mf = 0; mf < 8; mf++) {
        int Rbase = bm + wr * 128 + mf * 16 + lg * 4;
#pragma unroll
        for (int nf = 0; nf < 4; nf++) {
            int Cg = bn + wc * 64 + nf * 16 + l15;
            float bv = bias[Cg];
            if (EPI == 0) {
                int s = Cg / 768; int rem = Cg - s * 768; int h = rem >> 5; int dd = rem & 31;
#pragma unroll
                for (int rg = 0; rg < 4; rg++) {
                    int R = Rbase + rg;
                    int w2 = R / 144; int nn = R - w2 * 144;
                    float v = acc[mf][nf][rg] + bv;
                    if (s == 0)      o0[((size_t)(w2 * 24 + h) * 144 + nn) * 32 + dd] = f2bf(v * qscale);
                    else if (s == 1) o1[((size_t)(w2 * 24 + h) * 144 + nn) * 32 + dd] = f2bf(v);
                    else             o2[((size_t)(w2 * 24 + h) * 32 + dd) * 144 + nn] = f2bf(v);
                }
            } else {
#pragma unroll
                for (int rg = 0; rg < 4; rg++) {
                    int R = Rbase + rg;
                    of[(size_t)R * Ndim + Cg] = acc[mf][nf][rg] + bv;
                }
            }
        }
    }
}

// ---------------- fused window attention: 1 block per (window, head), 9 waves ----------------
__global__ __launch_bounds__(576) void attn_kernel(const u16* __restrict__ Qg, const u16* __restrict__ Kg,
                                                   const u16* __restrict__ Vg, const float* __restrict__ bias_mat,
                                                   u16* __restrict__ Ob) {
    __shared__ __align__(16) u16 Qs[144 * 40];
    __shared__ __align__(16) u16 Ks[144 * 40];
    __shared__ __align__(16) u16 Vs[32 * 160];
    __shared__ __align__(16) u16 Ps[144 * 160];
    const int bx = blockIdx.x;
    const int w = bx / 24, h = bx - w * 24;
    const int wi = w & 3, wh = wi >> 1, ww = wi & 1;
    const int t = threadIdx.x, lane = t & 63, wv = t >> 6;
    const int l15 = lane & 15, lg = lane >> 4;
    const size_t base = (size_t)bx * 4608;
    {
        int nn = t >> 2, dd = (t & 3) << 3;
        *(u16x8*)(Qs + nn * 40 + dd) = *(const u16x8*)(Qg + base + nn * 32 + dd);
        *(u16x8*)(Ks + nn * 40 + dd) = *(const u16x8*)(Kg + base + nn * 32 + dd);
        int rv = t / 18, cv = (t - rv * 18) * 8;
        int ba = (rv * 320 + cv * 2) ^ ((rv & 7) << 4);
        *(u16x8*)((char*)Vs + ba) = *(const u16x8*)(Vg + base + rv * 144 + cv);
    }
    u16x8 zz = (u16x8)0;
    if (t < 64)  { int rv = t >> 1, cv = 144 + (t & 1) * 8; int ba = (rv * 320 + cv * 2) ^ ((rv & 7) << 4); *(u16x8*)((char*)Vs + ba) = zz; }
    if (t < 288) { int rv = t >> 1, cv = 144 + (t & 1) * 8; int ba = (rv * 320 + cv * 2) ^ ((rv & 7) << 4); *(u16x8*)((char*)Ps + ba) = zz; }
    __syncthreads();

    f32x4 S[9];
    {
        bf16x8 aq = *(const bf16x8*)(Qs + (wv * 16 + l15) * 40 + lg * 8);
        f32x4 z4 = (f32x4)0.0f;
#pragma unroll
        for (int j = 0; j < 9; j++) {
            bf16x8 bk = *(const bf16x8*)(Ks + (j * 16 + l15) * 40 + lg * 8);
            S[j] = __builtin_amdgcn_mfma_f32_16x16x32_bf16(aq, bk, z4, 0, 0, 0);
        }
    }
    int regm[9];
#pragma unroll
    for (int j = 0; j < 9; j++) {
        int m = j * 16 + l15; int r = m / 12, c = m - r * 12;
        int rid = wh ? (r < 6 ? 1 : 2) : 0;
        int cid = ww ? (c < 6 ? 1 : 2) : 0;
        regm[j] = rid * 3 + cid;
    }
    const float* bh = bias_mat + h * 20736;
#pragma unroll
    for (int rg = 0; rg < 4; rg++) {
        int n = wv * 16 + lg * 4 + rg;
        int r = n / 12, c = n - r * 12;
        int rid = wh ? (r < 6 ? 1 : 2) : 0;
        int cid = ww ? (c < 6 ? 1 : 2) : 0;
        int regn = rid * 3 + cid;
        const float* bhn = bh + n * 144;
        float mx = -1e30f;
#pragma unroll
        for (int j = 0; j < 9; j++) {
            float v = S[j][rg] + bhn[j * 16 + l15];
            if (regn != regm[j]) v -= 100.0f;
            S[j][rg] = v;
            mx = fmaxf(mx, v);
        }
#pragma unroll
        for (int d = 1; d < 16; d <<= 1) mx = fmaxf(mx, __shfl_xor(mx, d));
        float sum = 0.0f;
#pragma unroll
        for (int j = 0; j < 9; j++) { float e = __expf(S[j][rg] - mx); S[j][rg] = e; sum += e; }
#pragma unroll
        for (int d = 1; d < 16; d <<= 1) sum += __shfl_xor(sum, d);
        float inv = 1.0f / sum;
#pragma unroll
        for (int j = 0; j < 9; j++) {
            int ba = (n * 320 + (j * 16 + l15) * 2) ^ ((n & 7) << 4);
            *(u16*)((char*)Ps + ba) = f2bf(S[j][rg] * inv);
        }
    }
    __syncthreads();
    f32x4 o0 = (f32x4)0.0f, o1 = (f32x4)0.0f;
#pragma unroll
    for (int ks = 0; ks < 5; ks++) {
        int k2 = (ks * 32 + lg * 8) * 2;
        int ra = wv * 16 + l15;
        bf16x8 ap = *(const bf16x8*)((char*)Ps + ((ra * 320 + k2) ^ ((ra & 7) << 4)));
        int rv0 = l15, rv1 = 16 + l15;
        bf16x8 b0 = *(const bf16x8*)((char*)Vs + ((rv0 * 320 + k2) ^ ((rv0 & 7) << 4)));
        bf16x8 b1 = *(const bf16x8*)((char*)Vs + ((rv1 * 320 + k2) ^ ((rv1 & 7) << 4)));
        o0 = __builtin_amdgcn_mfma_f32_16x16x32_bf16(ap, b0, o0, 0, 0, 0);
        o1 = __builtin_amdgcn_mfma_f32_16x16x32_bf16(ap, b1, o1, 0, 0, 0);
    }
    size_t ob = (size_t)w * 110592 + (size_t)h * 32;
#pragma unroll
    for (int rg = 0; rg < 4; rg++) {
        int n = wv * 16 + lg * 4 + rg;
        Ob[ob + (size_t)n * 768 + l15]      = f2bf(o0[rg]);
        Ob[ob + (size_t)n * 768 + 16 + l15] = f2bf(o1[rg]);
    }
}

// ---------------- L2 norm + window-merge + reverse shift ----------------
__global__ __launch_bounds__(256) void norm_kernel(const float* __restrict__ raw, float* __restrict__ out) {
    int R = blockIdx.x * 4 + (threadIdx.x >> 6);
    int lane = threadIdx.x & 63;
    const float* src = raw + (size_t)R * 768;
    f32x4 v0 = *(const f32x4*)(src + lane * 4);
    f32x4 v1 = *(const f32x4*)(src + lane * 4 + 256);
    f32x4 v2 = *(const f32x4*)(src + lane * 4 + 512);
    float ss = v0[0]*v0[0] + v0[1]*v0[1] + v0[2]*v0[2] + v0[3]*v0[3]
             + v1[0]*v1[0] + v1[1]*v1[1] + v1[2]*v1[2] + v1[3]*v1[3]
             + v2[0]*v2[0] + v2[1]*v2[1] + v2[2]*v2[2] + v2[3]*v2[3];
#pragma unroll
    for (int d = 1; d < 64; d <<= 1) ss += __shfl_xor(ss, d);
    float inv = 1.0f / sqrtf(ss + 1e-6f);
    int w = R / 144, nn = R - w * 144;
    int b = w >> 2, wi = w & 3;
    int r = nn / 12, cc = nn - r * 12;
    int oh = (wi >> 1) * 12 + r + 6; if (oh >= 24) oh -= 24;
    int ow = (wi & 1) * 12 + cc + 6; if (ow >= 24) ow -= 24;
    float* dst = out + (((size_t)b * 24 + oh) * 24 + ow) * 768;
    v0 *= inv; v1 *= inv; v2 *= inv;
    *(f32x4*)(dst + lane * 4) = v0;
    *(f32x4*)(dst + lane * 4 + 256) = v1;
    *(f32x4*)(dst + lane * 4 + 512) = v2;
}

extern "C" void kernel_launch(void* const* d_in, const int* in_sizes, int n_in,
                              void* d_out, int out_size, void* d_ws, size_t ws_size,
                              hipStream_t stream) {
    const float* x      = (const float*)d_in[0];
    const float* qkv_w  = (const float*)d_in[1];
    const float* qkv_b  = (const float*)d_in[2];
    const float* proj_w = (const float*)d_in[3];
    const float* proj_b = (const float*)d_in[4];
    const float* rpb    = (const float*)d_in[5];
    const int*   rel    = (const int*)d_in[6];

    char* ws = (char*)d_ws;
    const size_t SZ = 56623104;  // 36864*768*2 bytes
    u16*   xw   = (u16*)(ws);
    u16*   Qb   = (u16*)(ws + SZ);
    u16*   Kb   = (u16*)(ws + 2 * SZ);
    u16*   Vt   = (u16*)(ws + 3 * SZ);
    u16*   Ob   = (u16*)(ws + 4 * SZ);
    u16*   qwt  = (u16*)(ws + 5 * SZ);
    u16*   pwt  = (u16*)(ws + 5 * SZ + 3538944);
    float* bm   = (float*)(ws + 5 * SZ + 3538944 + 1179648);
    float* raw  = (float*)(ws);  // aliases xw+Qb (dead by GEMM2)

    prep_x_kernel<<<27648, 256, 0, stream>>>(x, xw);
    transpose_cast_kernel<<<dim3(72, 24), 256, 0, stream>>>(qkv_w, qwt, 768, 2304);
    transpose_cast_kernel<<<dim3(24, 24), 256, 0, stream>>>(proj_w, pwt, 768, 768);
    make_bias_kernel<<<1944, 256, 0, stream>>>(rpb, rel, bm);

    gemm256_kernel<0><<<1296, 512, 0, stream>>>(xw, qwt, qkv_b, Qb, Kb, Vt, nullptr,
                                                2304, 768, 9, 0.17677669529663687f);
    attn_kernel<<<6144, 576, 0, stream>>>(Qb, Kb, Vt, bm, Ob);
    gemm256_kernel<1><<<432, 512, 0, stream>>>(Ob, pwt, proj_b, nullptr, nullptr, nullptr,
                                               raw, 768, 768, 3, 1.0f);
    norm_kernel<<<9216, 256, 0, stream>>>(raw, (float*)d_out);
}

// Round 3
// 504.043 us; speedup vs baseline: 1.0667x; 1.0262x over previous
//
#include <hip/hip_runtime.h>

typedef unsigned short u16;
typedef __bf16 bf16x8 __attribute__((ext_vector_type(8)));
typedef float f32x4 __attribute__((ext_vector_type(4)));
typedef u16 u16x8 __attribute__((ext_vector_type(8)));
typedef u16 u16x4 __attribute__((ext_vector_type(4)));

__device__ __forceinline__ u16 f2bf(float f) {
    union { float f; unsigned u; } v; v.f = f;
    unsigned r = v.u + 0x7FFFu + ((v.u >> 16) & 1u);
    return (u16)(r >> 16);
}

#define AS1 __attribute__((address_space(1)))
#define AS3 __attribute__((address_space(3)))
__device__ __forceinline__ void gload_lds16(const void* g, void* l) {
    __builtin_amdgcn_global_load_lds((const AS1 void*)(g), (AS3 void*)(l), 16, 0, 0);
}

// ---------------- prep: roll(-6,-6) + window partition + cast to bf16 ----------------
__global__ __launch_bounds__(256) void prep_x_kernel(const float* __restrict__ x, u16* __restrict__ xw) {
    unsigned i = ((unsigned)blockIdx.x * 256u + threadIdx.x) * 4u;
    int R = (int)(i / 768u); int c = (int)(i % 768u);
    int w = R / 144, nn = R - w * 144;
    int b = w >> 2, wi = w & 3;
    int r = nn / 12, cc = nn - r * 12;
    int sh = (wi >> 1) * 12 + r + 6; if (sh >= 24) sh -= 24;
    int sw = (wi & 1) * 12 + cc + 6; if (sw >= 24) sw -= 24;
    const float* src = x + (((size_t)b * 24 + sh) * 24 + sw) * 768 + c;
    f32x4 v = *(const f32x4*)src;
    u16x4 o; o[0] = f2bf(v[0]); o[1] = f2bf(v[1]); o[2] = f2bf(v[2]); o[3] = f2bf(v[3]);
    *(u16x4*)(xw + i) = o;
}

// ---------------- weight transpose + cast: w[K][N] -> wt[N][K] bf16 ----------------
__global__ __launch_bounds__(256) void transpose_cast_kernel(const float* __restrict__ w, u16* __restrict__ wt,
                                                             int K, int N) {
    __shared__ float tile[32][33];
    int tx = threadIdx.x & 31, ty = threadIdx.x >> 5;
    int nb = blockIdx.x * 32, kb = blockIdx.y * 32;
#pragma unroll
    for (int rr = 0; rr < 32; rr += 8) tile[rr + ty][tx] = w[(size_t)(kb + rr + ty) * N + nb + tx];
    __syncthreads();
#pragma unroll
    for (int rr = 0; rr < 32; rr += 8) wt[(size_t)(nb + rr + ty) * K + kb + tx] = f2bf(tile[tx][rr + ty]);
}

// ---------------- bias_mat[h][n][m] = rpb_table[rel_index[n*144+m]][h] ----------------
__global__ __launch_bounds__(256) void make_bias_kernel(const float* __restrict__ tab, const int* __restrict__ rel,
                                                        float* __restrict__ bm) {
    int i = blockIdx.x * 256 + threadIdx.x;
    int h = i / 20736, nm = i - h * 20736;
    bm[i] = tab[rel[nm] * 24 + h];
}

// ---------------- 256x256 BK=64 8-phase bf16 MFMA GEMM (T2+T3+T4+T5), Bt layout ----------------
// LDS: 2 buffers x 64KB; buffer b: A region [256r x 128B] at b*65536, B region at +32768.
// Swizzle (G4 form): region byte x at row r stored at x ^ ((r&7)<<4) — bijective per row,
// spreads 16-row fragment reads across all 8 16B slots (2 rows/slot = free 2-way).
// Store side: linear LDS dest + inverse-permuted global source (rule #21).
#define FENCE asm volatile("" ::: "memory")
#define BARRIER __builtin_amdgcn_s_barrier()

#define STAGE_HALF(g, rowbase, region, buf, T, h)                                              \
    { _Pragma("unroll") for (int j = 0; j < 2; j++) {                                          \
        int Lb = (h) * 16384 + (j * 8 + wv) * 1024;                                            \
        int L = Lb + lane * 16;                                                                \
        int Ls = L ^ (((L >> 7) & 7) << 4);                                                    \
        const u16* src = (g) + (size_t)((rowbase) + (Ls >> 7)) * Kdim + (T) * 64 + ((Ls & 127) >> 1); \
        gload_lds16(src, (char*)lds + (buf) * 65536 + (region) + Lb);                          \
    } }

#define READ_A(buf, mh)                                                                        \
    { _Pragma("unroll") for (int mf = 0; mf < 4; mf++) {                                       \
        _Pragma("unroll") for (int kk = 0; kk < 2; kk++) {                                     \
            int row = wr * 128 + (mh) * 64 + mf * 16 + l15;                                    \
            int cb = kk * 64 + lg * 16;                                                        \
            aR[mf][kk] = *(const bf16x8*)((const char*)lds + (buf) * 65536 + row * 128 + (cb ^ ((row & 7) << 4))); \
    } } }

#define READ_B(buf, nh)                                                                        \
    { _Pragma("unroll") for (int nf = 0; nf < 2; nf++) {                                       \
        _Pragma("unroll") for (int kk = 0; kk < 2; kk++) {                                     \
            int row = wc * 64 + (nh) * 32 + nf * 16 + l15;                                     \
            int cb = kk * 64 + lg * 16;                                                        \
            bR[nh][nf][kk] = *(const bf16x8*)((const char*)lds + (buf) * 65536 + 32768 + row * 128 + (cb ^ ((row & 7) << 4))); \
    } } }

#define MFMA_QUAD(mh, nh)                                                                      \
    { __builtin_amdgcn_s_setprio(1);                                                           \
      _Pragma("unroll") for (int mf = 0; mf < 4; mf++) {                                       \
        _Pragma("unroll") for (int nf = 0; nf < 2; nf++) {                                     \
            _Pragma("unroll") for (int kk = 0; kk < 2; kk++) {                                 \
                acc[(mh) * 4 + mf][(nh) * 2 + nf] = __builtin_amdgcn_mfma_f32_16x16x32_bf16(   \
                    aR[mf][kk], bR[nh][nf][kk], acc[(mh) * 4 + mf][(nh) * 2 + nf], 0, 0, 0);   \
      } } }                                                                                    \
      __builtin_amdgcn_s_setprio(0); }

template <int EPI>
__global__ __launch_bounds__(512, 2) void gemm256_kernel(const u16* __restrict__ A, const u16* __restrict__ Bt,
                                                         const float* __restrict__ bias,
                                                         u16* __restrict__ o0, u16* __restrict__ o1, u16* __restrict__ o2,
                                                         float* __restrict__ of, int Ndim, int Kdim, int nxb, float qscale) {
    __shared__ __align__(16) u16 lds[65536];  // 128 KiB
    const int t = threadIdx.x, lane = t & 63, wv = t >> 6;
    const int wr = wv >> 2, wc = wv & 3;          // 2 x 4 wave grid
    const int l15 = lane & 15, lg = lane >> 4;
    int nwg = gridDim.x, orig = blockIdx.x;       // bijective XCD swizzle
    int q = nwg >> 3, r = nwg & 7, xcd = orig & 7, loc = orig >> 3;
    int wg = (xcd < r ? xcd * (q + 1) : r * (q + 1) + (xcd - r) * q) + loc;
    int by = wg / nxb, bx = wg - by * nxb;
    const int bm = by << 8, bn = bx << 8;

    f32x4 acc[8][4] = {};
    bf16x8 aR[4][2];
    bf16x8 bR[2][2][2];

    const int NT = Kdim >> 6;
    const int NITER = NT >> 1;

    // prologue: T0 (all 4 halves) + T1 B0,A0
    STAGE_HALF(A, bm, 0, 0, 0, 0);
    STAGE_HALF(A, bm, 0, 0, 0, 1);
    STAGE_HALF(Bt, bn, 32768, 0, 0, 0);
    STAGE_HALF(Bt, bn, 32768, 0, 0, 1);
    STAGE_HALF(Bt, bn, 32768, 1, 1, 0);
    STAGE_HALF(A, bm, 0, 1, 1, 0);
    asm volatile("s_waitcnt vmcnt(4)" ::: "memory");
    FENCE; BARRIER;

    for (int i = 0; i < NITER; i++) {
        const int u = 2 * i + 1, t2 = 2 * i + 2, t3 = 2 * i + 3;
        const bool last = (i == NITER - 1);
        // ---- tile 2i from buf0 ----
        // p1
        STAGE_HALF(Bt, bn, 32768, 1, u, 1);
        READ_A(0, 0); READ_B(0, 0);
        FENCE; BARRIER;
        MFMA_QUAD(0, 0);
        FENCE; BARRIER;
        // p2
        STAGE_HALF(A, bm, 0, 1, u, 1);
        READ_B(0, 1);
        FENCE; BARRIER;
        MFMA_QUAD(0, 1);
        FENCE; BARRIER;
        // p3
        if (t2 < NT) STAGE_HALF(Bt, bn, 32768, 0, t2, 0);
        READ_A(0, 1);
        FENCE; BARRIER;
        MFMA_QUAD(1, 0);
        FENCE; BARRIER;
        // p4
        if (t2 < NT) STAGE_HALF(A, bm, 0, 0, t2, 0);
        FENCE; BARRIER;
        MFMA_QUAD(1, 1);
        if (last) { asm volatile("s_waitcnt vmcnt(0)" ::: "memory"); }
        else      { asm volatile("s_waitcnt vmcnt(4)" ::: "memory"); }
        FENCE; BARRIER;
        // ---- tile 2i+1 from buf1 ----
        // p5
        if (t2 < NT) STAGE_HALF(Bt, bn, 32768, 0, t2, 1);
        READ_A(1, 0); READ_B(1, 0);
        FENCE; BARRIER;
        MFMA_QUAD(0, 0);
        FENCE; BARRIER;
        // p6
        if (t2 < NT) STAGE_HALF(A, bm, 0, 0, t2, 1);
        READ_B(1, 1);
        FENCE; BARRIER;
        MFMA_QUAD(0, 1);
        FENCE; BARRIER;
        // p7
        if (t3 < NT) STAGE_HALF(Bt, bn, 32768, 1, t3, 0);
        READ_A(1, 1);
        FENCE; BARRIER;
        MFMA_QUAD(1, 0);
        FENCE; BARRIER;
        // p8
        if (t3 < NT) STAGE_HALF(A, bm, 0, 1, t3, 0);
        FENCE; BARRIER;
        MFMA_QUAD(1, 1);
        asm volatile("s_waitcnt vmcnt(4)" ::: "memory");
        FENCE; BARRIER;
    }

    // epilogue
#pragma unroll
    for (int mf = 0; mf < 8; mf++) {
        int Rbase = bm + wr * 128 + mf * 16 + lg * 4;
#pragma unroll
        for (int nf = 0; nf < 4; nf++) {
            int Cg = bn + wc * 64 + nf * 16 + l15;
            float bv = bias[Cg];
            if (EPI == 0) {
                int s = Cg / 768; int rem = Cg - s * 768; int h = rem >> 5; int dd = rem & 31;
#pragma unroll
                for (int rg = 0; rg < 4; rg++) {
                    int R = Rbase + rg;
                    int w2 = R / 144; int nn = R - w2 * 144;
                    float v = acc[mf][nf][rg] + bv;
                    if (s == 0)      o0[((size_t)(w2 * 24 + h) * 144 + nn) * 32 + dd] = f2bf(v * qscale);
                    else if (s == 1) o1[((size_t)(w2 * 24 + h) * 144 + nn) * 32 + dd] = f2bf(v);
                    else             o2[((size_t)(w2 * 24 + h) * 32 + dd) * 144 + nn] = f2bf(v);
                }
            } else {
#pragma unroll
                for (int rg = 0; rg < 4; rg++) {
                    int R = Rbase + rg;
                    of[(size_t)R * Ndim + Cg] = acc[mf][nf][rg] + bv;
                }
            }
        }
    }
}

// ---------------- fused window attention: 1 block per (window, head), 9 waves ----------------
__global__ __launch_bounds__(576) void attn_kernel(const u16* __restrict__ Qg, const u16* __restrict__ Kg,
                                                   const u16* __restrict__ Vg, const float* __restrict__ bias_mat,
                                                   u16* __restrict__ Ob) {
    __shared__ __align__(16) u16 Qs[144 * 40];
    __shared__ __align__(16) u16 Ks[144 * 40];
    __shared__ __align__(16) u16 Vs[32 * 160];
    __shared__ __align__(16) u16 Ps[144 * 160];
    const int bx = blockIdx.x;
    const int w = bx / 24, h = bx - w * 24;
    const int wi = w & 3, wh = wi >> 1, ww = wi & 1;
    const int t = threadIdx.x, lane = t & 63, wv = t >> 6;
    const int l15 = lane & 15, lg = lane >> 4;
    const size_t base = (size_t)bx * 4608;
    {
        int nn = t >> 2, dd = (t & 3) << 3;
        *(u16x8*)(Qs + nn * 40 + dd) = *(const u16x8*)(Qg + base + nn * 32 + dd);
        *(u16x8*)(Ks + nn * 40 + dd) = *(const u16x8*)(Kg + base + nn * 32 + dd);
        int rv = t / 18, cv = (t - rv * 18) * 8;
        int ba = (rv * 320 + cv * 2) ^ ((rv & 7) << 4);
        *(u16x8*)((char*)Vs + ba) = *(const u16x8*)(Vg + base + rv * 144 + cv);
    }
    u16x8 zz = (u16x8)0;
    if (t < 64)  { int rv = t >> 1, cv = 144 + (t & 1) * 8; int ba = (rv * 320 + cv * 2) ^ ((rv & 7) << 4); *(u16x8*)((char*)Vs + ba) = zz; }
    if (t < 288) { int rv = t >> 1, cv = 144 + (t & 1) * 8; int ba = (rv * 320 + cv * 2) ^ ((rv & 7) << 4); *(u16x8*)((char*)Ps + ba) = zz; }
    __syncthreads();

    f32x4 S[9];
    {
        bf16x8 aq = *(const bf16x8*)(Qs + (wv * 16 + l15) * 40 + lg * 8);
        f32x4 z4 = (f32x4)0.0f;
#pragma unroll
        for (int j = 0; j < 9; j++) {
            bf16x8 bk = *(const bf16x8*)(Ks + (j * 16 + l15) * 40 + lg * 8);
            S[j] = __builtin_amdgcn_mfma_f32_16x16x32_bf16(aq, bk, z4, 0, 0, 0);
        }
    }
    int regm[9];
#pragma unroll
    for (int j = 0; j < 9; j++) {
        int m = j * 16 + l15; int r = m / 12, c = m - r * 12;
        int rid = wh ? (r < 6 ? 1 : 2) : 0;
        int cid = ww ? (c < 6 ? 1 : 2) : 0;
        regm[j] = rid * 3 + cid;
    }
    const float* bh = bias_mat + h * 20736;
#pragma unroll
    for (int rg = 0; rg < 4; rg++) {
        int n = wv * 16 + lg * 4 + rg;
        int r = n / 12, c = n - r * 12;
        int rid = wh ? (r < 6 ? 1 : 2) : 0;
        int cid = ww ? (c < 6 ? 1 : 2) : 0;
        int regn = rid * 3 + cid;
        const float* bhn = bh + n * 144;
        float mx = -1e30f;
#pragma unroll
        for (int j = 0; j < 9; j++) {
            float v = S[j][rg] + bhn[j * 16 + l15];
            if (regn != regm[j]) v -= 100.0f;
            S[j][rg] = v;
            mx = fmaxf(mx, v);
        }
#pragma unroll
        for (int d = 1; d < 16; d <<= 1) mx = fmaxf(mx, __shfl_xor(mx, d));
        float sum = 0.0f;
#pragma unroll
        for (int j = 0; j < 9; j++) { float e = __expf(S[j][rg] - mx); S[j][rg] = e; sum += e; }
#pragma unroll
        for (int d = 1; d < 16; d <<= 1) sum += __shfl_xor(sum, d);
        float inv = 1.0f / sum;
#pragma unroll
        for (int j = 0; j < 9; j++) {
            int ba = (n * 320 + (j * 16 + l15) * 2) ^ ((n & 7) << 4);
            *(u16*)((char*)Ps + ba) = f2bf(S[j][rg] * inv);
        }
    }
    __syncthreads();
    f32x4 o0 = (f32x4)0.0f, o1 = (f32x4)0.0f;
#pragma unroll
    for (int ks = 0; ks < 5; ks++) {
        int k2 = (ks * 32 + lg * 8) * 2;
        int ra = wv * 16 + l15;
        bf16x8 ap = *(const bf16x8*)((char*)Ps + ((ra * 320 + k2) ^ ((ra & 7) << 4)));
        int rv0 = l15, rv1 = 16 + l15;
        bf16x8 b0 = *(const bf16x8*)((char*)Vs + ((rv0 * 320 + k2) ^ ((rv0 & 7) << 4)));
        bf16x8 b1 = *(const bf16x8*)((char*)Vs + ((rv1 * 320 + k2) ^ ((rv1 & 7) << 4)));
        o0 = __builtin_amdgcn_mfma_f32_16x16x32_bf16(ap, b0, o0, 0, 0, 0);
        o1 = __builtin_amdgcn_mfma_f32_16x16x32_bf16(ap, b1, o1, 0, 0, 0);
    }
    size_t ob = (size_t)w * 110592 + (size_t)h * 32;
#pragma unroll
    for (int rg = 0; rg < 4; rg++) {
        int n = wv * 16 + lg * 4 + rg;
        Ob[ob + (size_t)n * 768 + l15]      = f2bf(o0[rg]);
        Ob[ob + (size_t)n * 768 + 16 + l15] = f2bf(o1[rg]);
    }
}

// ---------------- L2 norm + window-merge + reverse shift ----------------
__global__ __launch_bounds__(256) void norm_kernel(const float* __restrict__ raw, float* __restrict__ out) {
    int R = blockIdx.x * 4 + (threadIdx.x >> 6);
    int lane = threadIdx.x & 63;
    const float* src = raw + (size_t)R * 768;
    f32x4 v0 = *(const f32x4*)(src + lane * 4);
    f32x4 v1 = *(const f32x4*)(src + lane * 4 + 256);
    f32x4 v2 = *(const f32x4*)(src + lane * 4 + 512);
    float ss = v0[0]*v0[0] + v0[1]*v0[1] + v0[2]*v0[2] + v0[3]*v0[3]
             + v1[0]*v1[0] + v1[1]*v1[1] + v1[2]*v1[2] + v1[3]*v1[3]
             + v2[0]*v2[0] + v2[1]*v2[1] + v2[2]*v2[2] + v2[3]*v2[3];
#pragma unroll
    for (int d = 1; d < 64; d <<= 1) ss += __shfl_xor(ss, d);
    float inv = 1.0f / sqrtf(ss + 1e-6f);
    int w = R / 144, nn = R - w * 144;
    int b = w >> 2, wi = w & 3;
    int r = nn / 12, cc = nn - r * 12;
    int oh = (wi >> 1) * 12 + r + 6; if (oh >= 24) oh -= 24;
    int ow = (wi & 1) * 12 + cc + 6; if (ow >= 24) ow -= 24;
    float* dst = out + (((size_t)b * 24 + oh) * 24 + ow) * 768;
    v0 *= inv; v1 *= inv; v2 *= inv;
    *(f32x4*)(dst + lane * 4) = v0;
    *(f32x4*)(dst + lane * 4 + 256) = v1;
    *(f32x4*)(dst + lane * 4 + 512) = v2;
}

extern "C" void kernel_launch(void* const* d_in, const int* in_sizes, int n_in,
                              void* d_out, int out_size, void* d_ws, size_t ws_size,
                              hipStream_t stream) {
    const float* x      = (const float*)d_in[0];
    const float* qkv_w  = (const float*)d_in[1];
    const float* qkv_b  = (const float*)d_in[2];
    const float* proj_w = (const float*)d_in[3];
    const float* proj_b = (const float*)d_in[4];
    const float* rpb    = (const float*)d_in[5];
    const int*   rel    = (const int*)d_in[6];

    char* ws = (char*)d_ws;
    const size_t SZ = 56623104;  // 36864*768*2 bytes
    u16*   xw   = (u16*)(ws);
    u16*   Qb   = (u16*)(ws + SZ);
    u16*   Kb   = (u16*)(ws + 2 * SZ);
    u16*   Vt   = (u16*)(ws + 3 * SZ);
    u16*   Ob   = (u16*)(ws + 4 * SZ);
    u16*   qwt  = (u16*)(ws + 5 * SZ);
    u16*   pwt  = (u16*)(ws + 5 * SZ + 3538944);
    float* bm   = (float*)(ws + 5 * SZ + 3538944 + 1179648);
    float* raw  = (float*)(ws);  // aliases xw+Qb (dead by GEMM2)

    prep_x_kernel<<<27648, 256, 0, stream>>>(x, xw);
    transpose_cast_kernel<<<dim3(72, 24), 256, 0, stream>>>(qkv_w, qwt, 768, 2304);
    transpose_cast_kernel<<<dim3(24, 24), 256, 0, stream>>>(proj_w, pwt, 768, 768);
    make_bias_kernel<<<1944, 256, 0, stream>>>(rpb, rel, bm);

    gemm256_kernel<0><<<1296, 512, 0, stream>>>(xw, qwt, qkv_b, Qb, Kb, Vt, nullptr,
                                                2304, 768, 9, 0.17677669529663687f);
    attn_kernel<<<6144, 576, 0, stream>>>(Qb, Kb, Vt, bm, Ob);
    gemm256_kernel<1><<<432, 512, 0, stream>>>(Ob, pwt, proj_b, nullptr, nullptr, nullptr,
                                               raw, 768, 768, 3, 1.0f);
    norm_kernel<<<9216, 256, 0, stream>>>(raw, (float*)d_out);
}